// Round 3
// baseline (344.001 us; speedup 1.0000x reference)
//
#include <hip/hip_runtime.h>

#define U_   2048
#define T_   200
#define S_   10
#define K_   20
#define H_   16
#define DU_  32
#define DE_  32
#define DIN_ 264   // 32 + 11 + 220 + 1

#define THREADS 256
#define WAVES_PER_BLK (THREADS / 64)
#define POS_PER_WAVE 64

// ---------------------------------------------------------------------------
// Kernel 1: pre[pos,h] = b_rnn[h] + x[pos,:] . Wx[:,h]
// One WAVE per position per iteration. Lane->column ownership:
//   lanes 0..49  : f[pos, 4l .. 4l+3]          (Wx rows 43+4l ..)
//   lanes 50..54 : q[pos, 2(l-50) .. +1]       (Wx rows 32+2(l-50) ..)
//   lanes 55..62 : emb[docid[pos], 4(l-55)..]  (Wx rows 4(l-55) ..)
//   lane  63     : ct[pos]                     (Wx row 263)
// Weights live in per-lane VGPRs (loaded once). No LDS, no barriers.
// ---------------------------------------------------------------------------
__device__ __forceinline__ float4 ldx(int pos, int l,
    const float* __restrict__ f, const float* __restrict__ q,
    const int* __restrict__ docid, const float* __restrict__ ct,
    const float* __restrict__ emb)
{
    float4 v;
    if (l < 50) {
        v = *(const float4*)(f + (size_t)pos * 200 + 4 * l);
    } else if (l < 55) {
        float2 t = *(const float2*)(q + (size_t)pos * 10 + 2 * (l - 50));
        v = make_float4(t.x, t.y, 0.f, 0.f);
    } else if (l < 63) {
        int did = docid[pos];                       // wave-uniform -> s_load
        v = *(const float4*)(emb + (size_t)did * DE_ + 4 * (l - 55));
    } else {
        v = make_float4(ct[pos], 0.f, 0.f, 0.f);    // wave-uniform
    }
    return v;
}

__global__ __launch_bounds__(THREADS) void k_pre(
    const float* __restrict__ q, const float* __restrict__ f,
    const int* __restrict__ docid, const float* __restrict__ ct,
    const float* __restrict__ emb, const float* __restrict__ Wx,
    const float* __restrict__ brnn, float* __restrict__ pre)
{
    const int tid = threadIdx.x;
    const int l = tid & 63;
    const int wid = blockIdx.x * WAVES_PER_BLK + (tid >> 6);
    const int pbeg = wid * POS_PER_WAVE;
    const int pend = pbeg + POS_PER_WAVE;

    // ---- per-lane weight rows (one-time) ----
    int r0, nr;
    if (l < 50)      { r0 = 43 + 4 * l;        nr = 4; }
    else if (l < 55) { r0 = 32 + 2 * (l - 50); nr = 2; }
    else if (l < 63) { r0 = 4 * (l - 55);      nr = 4; }
    else             { r0 = 263;               nr = 1; }

    float w0[16], w1[16], w2[16], w3[16];
    {
        const int r1 = (nr > 1) ? r0 + 1 : r0;   // clamped (valid addr), zeroed below
        const int r2 = (nr > 2) ? r0 + 2 : r0;
        const int r3 = (nr > 3) ? r0 + 3 : r0;
#pragma unroll
        for (int h = 0; h < 16; ++h) {
            w0[h] = Wx[r0 * H_ + h];
            w1[h] = (nr > 1) ? Wx[r1 * H_ + h] : 0.f;
            w2[h] = (nr > 2) ? Wx[r2 * H_ + h] : 0.f;
            w3[h] = (nr > 3) ? Wx[r3 * H_ + h] : 0.f;
        }
    }

    // lane -> h mapping after split-butterfly: h = bitrev4(l & 15)
    const int hl = ((l & 1) << 3) | ((l & 2) << 1) | ((l & 4) >> 1) | ((l & 8) >> 3);
    const float bval = brnn[hl];

    float4 vc = ldx(pbeg, l, f, q, docid, ct, emb);

#pragma unroll 2
    for (int pos = pbeg; pos < pend; ++pos) {
        const int pn = (pos + 1 < pend) ? pos + 1 : pos;
        float4 vn = ldx(pn, l, f, q, docid, ct, emb);   // prefetch next

        // ---- partial products: pacc[h] = sum_j v[j] * w_j[h] ----
        float pacc[16];
#pragma unroll
        for (int h = 0; h < 16; ++h) pacc[h] = vc.x * w0[h];
#pragma unroll
        for (int h = 0; h < 16; ++h) pacc[h] += vc.y * w1[h];
#pragma unroll
        for (int h = 0; h < 16; ++h) pacc[h] += vc.z * w2[h];
#pragma unroll
        for (int h = 0; h < 16; ++h) pacc[h] += vc.w * w3[h];

        // ---- split-butterfly reduction across 64 lanes ----
        const bool b0 = (l & 1) != 0;
        float s8[8];
#pragma unroll
        for (int i = 0; i < 8; ++i) {
            float snd = b0 ? pacc[i] : pacc[i + 8];
            float kep = b0 ? pacc[i + 8] : pacc[i];
            s8[i] = kep + __shfl_xor(snd, 1);
        }
        const bool b1 = (l & 2) != 0;
        float s4[4];
#pragma unroll
        for (int i = 0; i < 4; ++i) {
            float snd = b1 ? s4[0] * 0.f + s8[i] : s8[i + 4];   // keep indices static
            float kep = b1 ? s8[i + 4] : s8[i];
            s4[i] = kep + __shfl_xor(snd, 2);
        }
        const bool b2 = (l & 4) != 0;
        float s2[2];
#pragma unroll
        for (int i = 0; i < 2; ++i) {
            float snd = b2 ? s4[i] : s4[i + 2];
            float kep = b2 ? s4[i + 2] : s4[i];
            s2[i] = kep + __shfl_xor(snd, 4);
        }
        const bool b3 = (l & 8) != 0;
        float s1;
        {
            float snd = b3 ? s2[0] : s2[1];
            float kep = b3 ? s2[1] : s2[0];
            s1 = kep + __shfl_xor(snd, 8);
        }
        s1 += __shfl_xor(s1, 16);
        s1 += __shfl_xor(s1, 32);

        if (l < 16) pre[(size_t)pos * H_ + hl] = s1 + bval;

        vc = vn;
    }
}

// ---------------------------------------------------------------------------
// Kernel 2: sequential RNN scan per user (16 lanes = 16 h-components),
// fused LeakyReLU + Dense(32).
// ---------------------------------------------------------------------------
__device__ __forceinline__ float tanh_fast(float x) {
    float e = __expf(2.f * x);
    return 1.f - 2.f / (e + 1.f);
}

__global__ __launch_bounds__(64) void k_rnn(
    const float* __restrict__ pre, const int* __restrict__ docid,
    const float* __restrict__ Wh, const float* __restrict__ Wd,
    const float* __restrict__ bd, float* __restrict__ out)
{
    const int tid = threadIdx.x;
    const int l = tid & 15;
    const int u = (blockIdx.x * 64 + tid) >> 4;

    const float* prow = pre + (size_t)u * T_ * H_;
    const int* drow = docid + (size_t)u * T_;

    float wh[16];
#pragma unroll
    for (int k = 0; k < 16; ++k) wh[k] = Wh[((l ^ k) << 4) | l];

    float h = 0.f;

    float pb0 = prow[0 * H_ + l], pb1 = prow[1 * H_ + l],
          pb2 = prow[2 * H_ + l], pb3 = prow[3 * H_ + l];
    int   m0 = drow[0], m1 = drow[1], m2 = drow[2], m3 = drow[3];

    for (int tb = 0; tb < T_; tb += 4) {
#pragma unroll
        for (int s = 0; s < 4; ++s) {
            float p; int m;
            if      (s == 0) { p = pb0; m = m0; }
            else if (s == 1) { p = pb1; m = m1; }
            else if (s == 2) { p = pb2; m = m2; }
            else             { p = pb3; m = m3; }

            int tn = tb + 4 + s; if (tn > T_ - 1) tn = T_ - 1;
            float pn = prow[tn * H_ + l];
            int   mn = drow[tn];
            if      (s == 0) { pb0 = pn; m0 = mn; }
            else if (s == 1) { pb1 = pn; m1 = mn; }
            else if (s == 2) { pb2 = pn; m2 = mn; }
            else             { pb3 = pn; m3 = mn; }

            float a0 = p, a1 = 0.f, a2 = 0.f, a3 = 0.f;
#pragma unroll
            for (int k = 0; k < 16; k += 4) {
                a0 += __shfl_xor(h, k + 0, 16) * wh[k + 0];
                a1 += __shfl_xor(h, k + 1, 16) * wh[k + 1];
                a2 += __shfl_xor(h, k + 2, 16) * wh[k + 2];
                a3 += __shfl_xor(h, k + 3, 16) * wh[k + 3];
            }
            float accv = (a0 + a1) + (a2 + a3);
            float th = tanh_fast(accv);
            h = (m != 0) ? th : h;
        }
    }

    float a = (h >= 0.f) ? h : 0.3f * h;

    float wd0[16], wd1[16];
#pragma unroll
    for (int k = 0; k < 16; ++k) {
        int j = l ^ k;
        wd0[k] = Wd[j * DU_ + l];
        wd1[k] = Wd[j * DU_ + l + 16];
    }
    float o0 = bd[l], o1 = bd[l + 16];
#pragma unroll
    for (int k = 0; k < 16; ++k) {
        float av = __shfl_xor(a, k, 16);
        o0 += av * wd0[k];
        o1 += av * wd1[k];
    }
    out[(size_t)u * DU_ + l] = o0;
    out[(size_t)u * DU_ + l + 16] = o1;
}

// ---------------------------------------------------------------------------
extern "C" void kernel_launch(void* const* d_in, const int* in_sizes, int n_in,
                              void* d_out, int out_size, void* d_ws, size_t ws_size,
                              hipStream_t stream) {
    const float* q     = (const float*)d_in[0];
    const float* f     = (const float*)d_in[1];
    const int*   docid = (const int*)  d_in[2];
    const float* ct    = (const float*)d_in[3];
    const float* emb   = (const float*)d_in[4];
    const float* Wx    = (const float*)d_in[5];
    const float* Wh    = (const float*)d_in[6];
    const float* brnn  = (const float*)d_in[7];
    const float* Wd    = (const float*)d_in[8];
    const float* bd    = (const float*)d_in[9];
    float* out = (float*)d_out;

    float* pre = (float*)d_ws;                   // U*T*H floats = 26.2 MB

    const int nwaves = (U_ * T_) / POS_PER_WAVE;            // 6400
    k_pre<<<nwaves / WAVES_PER_BLK, THREADS, 0, stream>>>(q, f, docid, ct, emb, Wx, brnn, pre);
    k_rnn<<<(U_ * H_) / 64, 64, 0, stream>>>(pre, docid, Wh, Wd, bd, out);
}

// Round 4
// 175.202 us; speedup vs baseline: 1.9635x; 1.9635x over previous
//
#include <hip/hip_runtime.h>

#define U_   2048
#define T_   200
#define S_   10
#define K_   20
#define H_   16
#define DU_  32
#define DE_  32
#define DIN_ 264   // 32 + 11 + 220 + 1

// ---------------------------------------------------------------------------
// Kernel 1: pre[pos,h] = b_rnn[h] + x[pos,:] . Wx[:,h]
// Thread-per-position (R1 skeleton). Weights read via WAVE-UNIFORM addresses
// -> compiler emits s_load through the scalar cache (R2's proven path).
// Zero LDS, zero barriers, zero shuffles: the LDS pipe (R1/R3 bottleneck)
// is completely idle. Each v_fmac = 1 SGPR (weight) x 2 VGPR.
// ---------------------------------------------------------------------------
__global__ __launch_bounds__(256) void k_pre(
    const float* __restrict__ q, const float* __restrict__ f,
    const int* __restrict__ docid, const float* __restrict__ ct,
    const float* __restrict__ emb, const float* __restrict__ Wx,
    const float* __restrict__ brnn, float* __restrict__ pre)
{
    const int idx = blockIdx.x * 256 + threadIdx.x;   // 1600 blocks exact

    float acc[H_];
#pragma unroll
    for (int h = 0; h < H_; ++h) acc[h] = brnn[h];    // uniform -> s_load

    // ---- features part first (bulk of HBM): Wx rows 43..242 ----
    {
        const float4* f4 = (const float4*)(f + (size_t)idx * (S_ * K_)); // 800B rows
#pragma unroll 5
        for (int r = 0; r < (S_ * K_) / 4; ++r) {
            float4 v = f4[r];
            const float* w = Wx + (DE_ + S_ + 1 + r * 4) * H_;   // uniform
#pragma unroll
            for (int h = 0; h < H_; ++h)
                acc[h] += v.x * w[h] + v.y * w[h + 16] + v.z * w[h + 32] + v.w * w[h + 48];
        }
    }

    // ---- embedding part: Wx rows 0..31 ----
    {
        const float4* e4 = (const float4*)(emb + (size_t)docid[idx] * DE_);
#pragma unroll
        for (int r = 0; r < DE_ / 4; ++r) {
            float4 v = e4[r];
            const float* w = Wx + (r * 4) * H_;                  // uniform
#pragma unroll
            for (int h = 0; h < H_; ++h)
                acc[h] += v.x * w[h] + v.y * w[h + 16] + v.z * w[h + 32] + v.w * w[h + 48];
        }
    }

    // ---- quality part: Wx rows 32..41 (row 42 is the appended zero) ----
    {
        const float2* q2 = (const float2*)(q + (size_t)idx * S_);
#pragma unroll
        for (int r = 0; r < S_ / 2; ++r) {
            float2 v = q2[r];
            const float* w = Wx + (DE_ + r * 2) * H_;            // uniform
#pragma unroll
            for (int h = 0; h < H_; ++h)
                acc[h] += v.x * w[h] + v.y * w[h + 16];
        }
    }

    // ---- ctime: Wx row 263 ----
    {
        float c = ct[idx];
        const float* w = Wx + (DIN_ - 1) * H_;                   // uniform
#pragma unroll
        for (int h = 0; h < H_; ++h) acc[h] += c * w[h];
    }

    float4* o = (float4*)(pre + (size_t)idx * H_);
    o[0] = make_float4(acc[0], acc[1], acc[2], acc[3]);
    o[1] = make_float4(acc[4], acc[5], acc[6], acc[7]);
    o[2] = make_float4(acc[8], acc[9], acc[10], acc[11]);
    o[3] = make_float4(acc[12], acc[13], acc[14], acc[15]);
}

// ---------------------------------------------------------------------------
// Kernel 2: sequential RNN scan per user (16 lanes = 16 h-components),
// fused LeakyReLU + Dense(32).  (unchanged; ~8 µs)
// ---------------------------------------------------------------------------
__device__ __forceinline__ float tanh_fast(float x) {
    float e = __expf(2.f * x);
    return 1.f - 2.f / (e + 1.f);
}

__global__ __launch_bounds__(64) void k_rnn(
    const float* __restrict__ pre, const int* __restrict__ docid,
    const float* __restrict__ Wh, const float* __restrict__ Wd,
    const float* __restrict__ bd, float* __restrict__ out)
{
    const int tid = threadIdx.x;
    const int l = tid & 15;
    const int u = (blockIdx.x * 64 + tid) >> 4;

    const float* prow = pre + (size_t)u * T_ * H_;
    const int* drow = docid + (size_t)u * T_;

    float wh[16];
#pragma unroll
    for (int k = 0; k < 16; ++k) wh[k] = Wh[((l ^ k) << 4) | l];

    float h = 0.f;

    float pb0 = prow[0 * H_ + l], pb1 = prow[1 * H_ + l],
          pb2 = prow[2 * H_ + l], pb3 = prow[3 * H_ + l];
    int   m0 = drow[0], m1 = drow[1], m2 = drow[2], m3 = drow[3];

    for (int tb = 0; tb < T_; tb += 4) {
#pragma unroll
        for (int s = 0; s < 4; ++s) {
            float p; int m;
            if      (s == 0) { p = pb0; m = m0; }
            else if (s == 1) { p = pb1; m = m1; }
            else if (s == 2) { p = pb2; m = m2; }
            else             { p = pb3; m = m3; }

            int tn = tb + 4 + s; if (tn > T_ - 1) tn = T_ - 1;
            float pn = prow[tn * H_ + l];
            int   mn = drow[tn];
            if      (s == 0) { pb0 = pn; m0 = mn; }
            else if (s == 1) { pb1 = pn; m1 = mn; }
            else if (s == 2) { pb2 = pn; m2 = mn; }
            else             { pb3 = pn; m3 = mn; }

            float a0 = p, a1 = 0.f, a2 = 0.f, a3 = 0.f;
#pragma unroll
            for (int k = 0; k < 16; k += 4) {
                a0 += __shfl_xor(h, k + 0, 16) * wh[k + 0];
                a1 += __shfl_xor(h, k + 1, 16) * wh[k + 1];
                a2 += __shfl_xor(h, k + 2, 16) * wh[k + 2];
                a3 += __shfl_xor(h, k + 3, 16) * wh[k + 3];
            }
            float accv = (a0 + a1) + (a2 + a3);
            float th = tanh_fast(accv);
            h = (m != 0) ? th : h;
        }
    }

    float a = (h >= 0.f) ? h : 0.3f * h;

    float wd0[16], wd1[16];
#pragma unroll
    for (int k = 0; k < 16; ++k) {
        int j = l ^ k;
        wd0[k] = Wd[j * DU_ + l];
        wd1[k] = Wd[j * DU_ + l + 16];
    }
    float o0 = bd[l], o1 = bd[l + 16];
#pragma unroll
    for (int k = 0; k < 16; ++k) {
        float av = __shfl_xor(a, k, 16);
        o0 += av * wd0[k];
        o1 += av * wd1[k];
    }
    out[(size_t)u * DU_ + l] = o0;
    out[(size_t)u * DU_ + l + 16] = o1;
}

// ---------------------------------------------------------------------------
extern "C" void kernel_launch(void* const* d_in, const int* in_sizes, int n_in,
                              void* d_out, int out_size, void* d_ws, size_t ws_size,
                              hipStream_t stream) {
    const float* q     = (const float*)d_in[0];
    const float* f     = (const float*)d_in[1];
    const int*   docid = (const int*)  d_in[2];
    const float* ct    = (const float*)d_in[3];
    const float* emb   = (const float*)d_in[4];
    const float* Wx    = (const float*)d_in[5];
    const float* Wh    = (const float*)d_in[6];
    const float* brnn  = (const float*)d_in[7];
    const float* Wd    = (const float*)d_in[8];
    const float* bd    = (const float*)d_in[9];
    float* out = (float*)d_out;

    float* pre = (float*)d_ws;                   // U*T*H floats = 26.2 MB

    k_pre<<<(U_ * T_) / 256, 256, 0, stream>>>(q, f, docid, ct, emb, Wx, brnn, pre);
    k_rnn<<<(U_ * H_) / 64, 64, 0, stream>>>(pre, docid, Wh, Wd, bd, out);
}